// Round 4
// baseline (1561.309 us; speedup 1.0000x reference)
//
#include <hip/hip_runtime.h>
#include <cstdint>
#include <cstddef>

#define NB 8
#define SL 1024
#define ED 1024
#define NH 16
#define DKH 64

typedef __attribute__((ext_vector_type(4))) float f32x4;
typedef __attribute__((ext_vector_type(8))) short short8;
typedef __attribute__((ext_vector_type(4))) short short4v;

__device__ __forceinline__ unsigned short bf16_rn(float x) {
    unsigned int u = __float_as_uint(x);
    u += 0x7FFFu + ((u >> 16) & 1u);
    return (unsigned short)(u >> 16);
}
__device__ __forceinline__ float bf16_f(unsigned short h) {
    return __uint_as_float(((unsigned int)h) << 16);
}
__device__ __forceinline__ void split2(float x, unsigned short& hi, unsigned short& lo) {
    unsigned short h = bf16_rn(x);
    hi = h;
    lo = bf16_rn(x - bf16_f(h));
}

// async global->LDS DMA, 16B per lane. LDS dest = wave-uniform base + lane*16 (linear).
__device__ __forceinline__ void dma16(const unsigned short* src, unsigned short* dst) {
    __builtin_amdgcn_global_load_lds(
        (const __attribute__((address_space(1))) void*)src,
        (__attribute__((address_space(3))) void*)dst,
        16, 0, 0);
}

template<int ROWS>
__device__ __forceinline__ void dma_plane(
    const unsigned short* __restrict__ g, unsigned short* l,
    int ld, int r0, int k0, int wave, int lane)
{
    for (int i = wave; i < ROWS / 16; i += 4) {
        const unsigned short* src =
            g + (size_t)(r0 + i * 16 + (lane >> 2)) * ld + k0 + (lane & 3) * 8;
        dma16(src, l + i * 512);
    }
}

// -------- GEMM core (verified round 2): BM x BN, BK=32, dbuf LDS + DMA --------
template<bool APRE, int BM, int BN, int WR, int WC, int ROWG, int COLT>
__device__ __forceinline__ void gemm_core3(
    unsigned short* smem,
    const float* __restrict__ Af,
    const unsigned short* __restrict__ Ahg, const unsigned short* __restrict__ Alg,
    int lda,
    const unsigned short* __restrict__ Bhg, const unsigned short* __restrict__ Blg,
    int ldb, int Kd, int m0, int n0,
    f32x4 (&acc)[ROWG][COLT])
{
    static_assert(WR * WC == 4, "4 waves");
    static_assert(16 * ROWG * WR == BM, "rows");
    static_assert(16 * COLT * WC == BN, "cols");
    static_assert(APRE || BM == 128, "fp32 staging assumes BM=128");

    constexpr int ASZ = BM * 32;
    constexpr int BSZ = BN * 32;
    unsigned short* Ah = smem;
    unsigned short* Al = smem + 2 * ASZ;
    unsigned short* Bh = smem + 4 * ASZ;
    unsigned short* Bl = smem + 4 * ASZ + 2 * BSZ;

    const int tid  = threadIdx.x;
    const int wave = tid >> 6;
    const int lane = tid & 63;
    const int quad = lane >> 4;
    const int l16  = lane & 15;
    const int wr   = wave / WC;
    const int wc   = wave % WC;

#pragma unroll
    for (int g = 0; g < ROWG; g++)
#pragma unroll
        for (int jt = 0; jt < COLT; jt++) acc[g][jt] = (f32x4)(0.0f);

    const int ar  = tid >> 1;
    const int acb = (tid & 1) * 2;

    auto load_a = [&](int kk, float4 st[4]) {
        const float* p = Af + (size_t)(m0 + ar) * lda + kk + (tid & 1) * 16;
        st[0] = *(const float4*)(p + 0);
        st[1] = *(const float4*)(p + 4);
        st[2] = *(const float4*)(p + 8);
        st[3] = *(const float4*)(p + 12);
    };
    auto write_a = [&](int b, const float4 st[4]) {
        unsigned short* dh = Ah + b * ASZ;
        unsigned short* dl = Al + b * ASZ;
#pragma unroll
        for (int w = 0; w < 2; w++) {
            const int csw = (acb + w) ^ ((ar >> 1) & 3);
            const float4 u0 = st[2 * w], u1 = st[2 * w + 1];
            short8 h8, l8;
            unsigned short h, l;
            split2(u0.x, h, l); h8[0] = (short)h; l8[0] = (short)l;
            split2(u0.y, h, l); h8[1] = (short)h; l8[1] = (short)l;
            split2(u0.z, h, l); h8[2] = (short)h; l8[2] = (short)l;
            split2(u0.w, h, l); h8[3] = (short)h; l8[3] = (short)l;
            split2(u1.x, h, l); h8[4] = (short)h; l8[4] = (short)l;
            split2(u1.y, h, l); h8[5] = (short)h; l8[5] = (short)l;
            split2(u1.z, h, l); h8[6] = (short)h; l8[6] = (short)l;
            split2(u1.w, h, l); h8[7] = (short)h; l8[7] = (short)l;
            *(short8*)&dh[ar * 32 + csw * 8] = h8;
            *(short8*)&dl[ar * 32 + csw * 8] = l8;
        }
    };
    auto stage_b = [&](int b, int kk) {
        dma_plane<BN>(Bhg, Bh + b * BSZ, ldb, n0, kk, wave, lane);
        dma_plane<BN>(Blg, Bl + b * BSZ, ldb, n0, kk, wave, lane);
    };
    auto stage_a_dma = [&](int b, int kk) {
        dma_plane<BM>(Ahg, Ah + b * ASZ, lda, m0, kk, wave, lane);
        dma_plane<BM>(Alg, Al + b * ASZ, lda, m0, kk, wave, lane);
    };

    if constexpr (APRE) {
        stage_a_dma(0, 0);
    } else {
        float4 st[4];
        load_a(0, st);
        write_a(0, st);
    }
    stage_b(0, 0);
    __syncthreads();

    int buf = 0;
    for (int k0 = 0; k0 < Kd; k0 += 32) {
        const int nk = k0 + 32;
        float4 st[4];
        if (nk < Kd) {
            if constexpr (APRE) stage_a_dma(buf ^ 1, nk);
            else                load_a(nk, st);
            stage_b(buf ^ 1, nk);
        }
        const unsigned short* pAh = Ah + buf * ASZ;
        const unsigned short* pAl = Al + buf * ASZ;
        const unsigned short* pBh = Bh + buf * BSZ;
        const unsigned short* pBl = Bl + buf * BSZ;
        short8 ah[ROWG], al[ROWG];
#pragma unroll
        for (int g = 0; g < ROWG; g++) {
            const int row = wr * (16 * ROWG) + g * 16 + l16;
            int co;
            if constexpr (APRE) co = quad * 8;
            else                co = (quad ^ ((row >> 1) & 3)) * 8;
            ah[g] = *(const short8*)&pAh[row * 32 + co];
            al[g] = *(const short8*)&pAl[row * 32 + co];
        }
#pragma unroll
        for (int jt = 0; jt < COLT; jt++) {
            const int brow = wc * (16 * COLT) + jt * 16 + l16;
            const short8 bh = *(const short8*)&pBh[brow * 32 + quad * 8];
            const short8 bl = *(const short8*)&pBl[brow * 32 + quad * 8];
#pragma unroll
            for (int g = 0; g < ROWG; g++) {
                acc[g][jt] = __builtin_amdgcn_mfma_f32_16x16x32_bf16(al[g], bh, acc[g][jt], 0, 0, 0);
                acc[g][jt] = __builtin_amdgcn_mfma_f32_16x16x32_bf16(ah[g], bl, acc[g][jt], 0, 0, 0);
                acc[g][jt] = __builtin_amdgcn_mfma_f32_16x16x32_bf16(ah[g], bh, acc[g][jt], 0, 0, 0);
            }
        }
        if constexpr (!APRE) {
            if (nk < Kd) write_a(buf ^ 1, st);
        }
        __syncthreads();
        buf ^= 1;
    }
}

// ---- weight transpose + split ----
__global__ __launch_bounds__(256)
void k_wsplitT(const float* __restrict__ W,
               unsigned short* __restrict__ Th, unsigned short* __restrict__ Tl)
{
    __shared__ float tile[64 * 65];
    const int n0 = blockIdx.x * 64;
    const int k0 = blockIdx.y * 64;
    const int tid = threadIdx.x;
    for (int i = tid; i < 64 * 64; i += 256) {
        const int rk = i >> 6, cn = i & 63;
        tile[rk * 65 + cn] = W[(size_t)(k0 + rk) * ED + n0 + cn];
    }
    __syncthreads();
    for (int i = tid; i < 64 * 64; i += 256) {
        const int rn = i >> 6, ck = i & 63;
        unsigned short h, l;
        split2(tile[ck * 65 + rn], h, l);
        Th[(size_t)(n0 + rn) * ED + k0 + ck] = h;
        Tl[(size_t)(n0 + rn) * ED + k0 + ck] = l;
    }
}

// ---- q/k projection ----
__global__ __launch_bounds__(256)
void k_projQK(const float* __restrict__ X,
              const unsigned short* __restrict__ Wh, const unsigned short* __restrict__ Wl,
              const float* __restrict__ bias,
              unsigned short* __restrict__ Oh, unsigned short* __restrict__ Ol)
{
    __shared__ unsigned short smem[(128 + 128) * 128];
    const int m0 = blockIdx.x * 128;
    const int n0 = blockIdx.y * 128;
    f32x4 acc[4][4];
    gemm_core3<false, 128, 128, 2, 2, 4, 4>(smem, X, nullptr, nullptr, ED,
                                            Wh, Wl, ED, ED, m0, n0, acc);

    const int tid = threadIdx.x, wave = tid >> 6, lane = tid & 63;
    const int quad = lane >> 4, l16 = lane & 15;
    const int wr = wave >> 1, wc = wave & 1;
#pragma unroll
    for (int jt = 0; jt < 4; jt++) {
        const int col = n0 + wc * 64 + jt * 16 + l16;
        const int h = col >> 6, d = col & 63;
        const float b = bias[col];
#pragma unroll
        for (int g = 0; g < 4; g++) {
#pragma unroll
            for (int rr = 0; rr < 4; rr++) {
                const int m = m0 + wr * 64 + g * 16 + quad * 4 + rr;
                const int n = m >> 10, s = m & 1023;
                const size_t idx = (((size_t)(n * NH + h)) * SL + s) * DKH + d;
                unsigned short hh, ll;
                split2(acc[g][jt][rr] + b, hh, ll);
                Oh[idx] = hh;
                Ol[idx] = ll;
            }
        }
    }
}

// ---- v projection: writes pre-split TRANSPOSED vT[ghead][d][s] ----
__global__ __launch_bounds__(256)
void k_projV(const float* __restrict__ X,
             const unsigned short* __restrict__ Wh, const unsigned short* __restrict__ Wl,
             const float* __restrict__ bias,
             unsigned short* __restrict__ Th, unsigned short* __restrict__ Tl)
{
    __shared__ unsigned short smem[(128 + 64) * 128];
    const int m0 = blockIdx.x * 128;
    const int n0 = blockIdx.y * 64;
    f32x4 acc[2][4];
    gemm_core3<false, 128, 64, 4, 1, 2, 4>(smem, X, nullptr, nullptr, ED,
                                           Wh, Wl, ED, ED, m0, n0, acc);

    unsigned int* T = (unsigned int*)smem;   // [128][65] packed (hi | lo<<16)
    const int tid = threadIdx.x, wave = tid >> 6, lane = tid & 63;
    const int quad = lane >> 4, l16 = lane & 15;
#pragma unroll
    for (int jt = 0; jt < 4; jt++) {
        const int d = jt * 16 + l16;
        const float b = bias[n0 + d];
#pragma unroll
        for (int g = 0; g < 2; g++) {
#pragma unroll
            for (int rr = 0; rr < 4; rr++) {
                const int sl = wave * 32 + g * 16 + quad * 4 + rr;
                unsigned short hh, ll;
                split2(acc[g][jt][rr] + b, hh, ll);
                T[sl * 65 + d] = (unsigned int)hh | ((unsigned int)ll << 16);
            }
        }
    }
    __syncthreads();
    const int d  = tid >> 2;
    const int sc = (tid & 3) * 32;
    const int ghead = (m0 >> 10) * NH + (n0 >> 6);
    const size_t rowbase = ((size_t)ghead * DKH + d) * SL + (m0 & 1023) + sc;
#pragma unroll
    for (int c = 0; c < 4; c++) {
        short8 h8, l8;
#pragma unroll
        for (int i = 0; i < 8; i++) {
            const unsigned int u = T[(sc + c * 8 + i) * 65 + d];
            h8[i] = (short)(u & 0xFFFFu);
            l8[i] = (short)(u >> 16);
        }
        *(short8*)(Th + rowbase + c * 8) = h8;
        *(short8*)(Tl + rowbase + c * 8) = l8;
    }
}

// ==== FUSED attention: logits + mask + softmax + attn-write + PV, one kernel ====
// Block = 32 q-rows x 1 head, 512 threads (8 waves): rg=wave>>2 (row-group of 16),
// cq=wave&3 (col-quarter of 256). acc[16] f32x4 per lane (64 VGPR) -> no spill.
// P bounced per-wave through LDS for (a) coalesced attn f32 stores,
// (b) C-layout -> A-frag transpose with split-on-read (each P elem split exactly once).
#define PFW 68   // LDS row stride (f32): 16B-aligned, odd 16B-groups -> low conflicts
__global__ __launch_bounds__(512)
void k_attn_fused(const unsigned short* __restrict__ qh_h, const unsigned short* __restrict__ qh_l,
                  const unsigned short* __restrict__ kh_h, const unsigned short* __restrict__ kh_l,
                  const unsigned short* __restrict__ vT_h, const unsigned short* __restrict__ vT_l,
                  const int* __restrict__ mask, float* __restrict__ attn,
                  unsigned short* __restrict__ Oh, unsigned short* __restrict__ Ol)
{
    __shared__ float Pf[8][16][PFW];   // per-wave-private chunk buffer; reused for O-combine
    __shared__ float MX[4][32];
    __shared__ float SMm[4][32];

    const int head = blockIdx.y;
    const int n = head >> 4, h = head & 15;
    const int m0 = blockIdx.x * 32;
    const int tid = threadIdx.x, wave = tid >> 6, lane = tid & 63;
    const int quad = lane >> 4, l16 = lane & 15;
    const int rg = wave >> 2, cq = wave & 3;

    const size_t hb = (size_t)head * SL * DKH;

    // ---- Q A-frags (2 k-chunks of 32) ----
    short8 qa_h[2], qa_l[2];
    {
        const unsigned short* qrh = qh_h + hb + (size_t)(m0 + rg * 16 + l16) * DKH + quad * 8;
        const unsigned short* qrl = qh_l + hb + (size_t)(m0 + rg * 16 + l16) * DKH + quad * 8;
#pragma unroll
        for (int kc = 0; kc < 2; kc++) {
            qa_h[kc] = *(const short8*)(qrh + kc * 32);
            qa_l[kc] = *(const short8*)(qrl + kc * 32);
        }
    }

    // ---- QK^T: 16 col-tiles of 16 (this wave's 256-col quarter), K=64 ----
    f32x4 acc[16];
    {
        const unsigned short* kbh = kh_h + hb + (size_t)(cq * 256 + l16) * DKH + quad * 8;
        const unsigned short* kbl = kh_l + hb + (size_t)(cq * 256 + l16) * DKH + quad * 8;
#pragma unroll
        for (int tt = 0; tt < 16; tt++) {
            const size_t toff = (size_t)tt * 16 * DKH;
            const short8 bh0 = *(const short8*)(kbh + toff);
            const short8 bl0 = *(const short8*)(kbl + toff);
            const short8 bh1 = *(const short8*)(kbh + toff + 32);
            const short8 bl1 = *(const short8*)(kbl + toff + 32);
            f32x4 a = (f32x4)(0.0f);
            a = __builtin_amdgcn_mfma_f32_16x16x32_bf16(qa_l[0], bh0, a, 0, 0, 0);
            a = __builtin_amdgcn_mfma_f32_16x16x32_bf16(qa_h[0], bl0, a, 0, 0, 0);
            a = __builtin_amdgcn_mfma_f32_16x16x32_bf16(qa_h[0], bh0, a, 0, 0, 0);
            a = __builtin_amdgcn_mfma_f32_16x16x32_bf16(qa_l[1], bh1, a, 0, 0, 0);
            a = __builtin_amdgcn_mfma_f32_16x16x32_bf16(qa_h[1], bl1, a, 0, 0, 0);
            a = __builtin_amdgcn_mfma_f32_16x16x32_bf16(qa_h[1], bh1, a, 0, 0, 0);
            acc[tt] = a;
        }
    }

    // ---- scale + mask ----
    const int* mrow0 = mask + ((size_t)n * SL + (m0 + rg * 16 + quad * 4 + 0)) * SL + cq * 256 + l16;
    const int* mrow1 = mrow0 + SL;
    const int* mrow2 = mrow1 + SL;
    const int* mrow3 = mrow2 + SL;
#pragma unroll
    for (int tt = 0; tt < 16; tt++) {
        const int t = tt * 16;
        float v0 = acc[tt][0] * 0.125f; if (mrow0[t]) v0 = -1e9f; acc[tt][0] = v0;
        float v1 = acc[tt][1] * 0.125f; if (mrow1[t]) v1 = -1e9f; acc[tt][1] = v1;
        float v2 = acc[tt][2] * 0.125f; if (mrow2[t]) v2 = -1e9f; acc[tt][2] = v2;
        float v3 = acc[tt][3] * 0.125f; if (mrow3[t]) v3 = -1e9f; acc[tt][3] = v3;
    }

    // ---- row max (per-wave quarter, then cross-quarter via LDS) ----
    float m4[4];
#pragma unroll
    for (int rr = 0; rr < 4; rr++) {
        float mx = -3.4e38f;
#pragma unroll
        for (int tt = 0; tt < 16; tt++) mx = fmaxf(mx, acc[tt][rr]);
#pragma unroll
        for (int o = 8; o > 0; o >>= 1) mx = fmaxf(mx, __shfl_xor(mx, o));
        m4[rr] = mx;
    }
    if (l16 < 4) {
        const float v = (l16 == 0) ? m4[0] : (l16 == 1) ? m4[1] : (l16 == 2) ? m4[2] : m4[3];
        MX[cq][rg * 16 + quad * 4 + l16] = v;
    }
    __syncthreads();
    float mc[4], sum4[4];
#pragma unroll
    for (int rr = 0; rr < 4; rr++) {
        const int r = rg * 16 + quad * 4 + rr;
        mc[rr] = fmaxf(fmaxf(MX[0][r], MX[1][r]), fmaxf(MX[2][r], MX[3][r]));
        sum4[rr] = 0.0f;
    }

    // ---- exp + row sum ----
#pragma unroll
    for (int tt = 0; tt < 16; tt++) {
#pragma unroll
        for (int rr = 0; rr < 4; rr++) {
            const float p = __expf(acc[tt][rr] - mc[rr]);
            acc[tt][rr] = p;
            sum4[rr] += p;
        }
    }
#pragma unroll
    for (int rr = 0; rr < 4; rr++) {
#pragma unroll
        for (int o = 8; o > 0; o >>= 1) sum4[rr] += __shfl_xor(sum4[rr], o);
    }
    if (l16 < 4) {
        const float v = (l16 == 0) ? sum4[0] : (l16 == 1) ? sum4[1] : (l16 == 2) ? sum4[2] : sum4[3];
        SMm[cq][rg * 16 + quad * 4 + l16] = v;
    }
    __syncthreads();
    float inv[4];
#pragma unroll
    for (int rr = 0; rr < 4; rr++) {
        const int r = rg * 16 + quad * 4 + rr;
        inv[rr] = 1.0f / (SMm[0][r] + SMm[1][r] + SMm[2][r] + SMm[3][r]);
    }

    // ---- PV + attn write, 4 chunks of 64 t-cols each ----
    f32x4 oac[4];
#pragma unroll
    for (int nt = 0; nt < 4; nt++) oac[nt] = (f32x4)(0.0f);

    const unsigned short* vbh = vT_h + (size_t)head * DKH * SL + (size_t)l16 * SL + cq * 256 + quad * 8;
    const unsigned short* vbl = vT_l + (size_t)head * DKH * SL + (size_t)l16 * SL + cq * 256 + quad * 8;
    float* aw = attn + ((size_t)head * SL + (m0 + rg * 16)) * SL + cq * 256;
    const int srow = lane >> 2;            // attn-store: row within wave's 16
    const int sseg = (lane & 3) * 16;      // 16-float segment

#pragma unroll
    for (int c = 0; c < 4; c++) {
        // (a) normalized P chunk -> per-wave-private LDS [16 rows][64 cols]
#pragma unroll
        for (int i = 0; i < 4; i++) {
            const int tt = c * 4 + i;
            Pf[wave][quad * 4 + 0][i * 16 + l16] = acc[tt][0] * inv[0];
            Pf[wave][quad * 4 + 1][i * 16 + l16] = acc[tt][1] * inv[1];
            Pf[wave][quad * 4 + 2][i * 16 + l16] = acc[tt][2] * inv[2];
            Pf[wave][quad * 4 + 3][i * 16 + l16] = acc[tt][3] * inv[3];
        }
        // (b) coalesced attn store: lane -> 16 consecutive floats of one row
        {
            float* dst = aw + (size_t)srow * SL + c * 64 + sseg;
            const float* srcb = &Pf[wave][srow][sseg];
            const f32x4 w0 = *(const f32x4*)(srcb + 0);
            const f32x4 w1 = *(const f32x4*)(srcb + 4);
            const f32x4 w2 = *(const f32x4*)(srcb + 8);
            const f32x4 w3 = *(const f32x4*)(srcb + 12);
            *(f32x4*)(dst + 0)  = w0;
            *(f32x4*)(dst + 4)  = w1;
            *(f32x4*)(dst + 8)  = w2;
            *(f32x4*)(dst + 12) = w3;
        }
        // (c) A-frag transpose read (split-on-read) + PV MFMA
#pragma unroll
        for (int ks = 0; ks < 2; ks++) {
            const float* pr = &Pf[wave][l16][ks * 32 + quad * 8];
            const f32x4 p0 = *(const f32x4*)(pr + 0);
            const f32x4 p1 = *(const f32x4*)(pr + 4);
            short8 ph, pl;
            {
                unsigned short hh, ll;
                split2(p0[0], hh, ll); ph[0] = (short)hh; pl[0] = (short)ll;
                split2(p0[1], hh, ll); ph[1] = (short)hh; pl[1] = (short)ll;
                split2(p0[2], hh, ll); ph[2] = (short)hh; pl[2] = (short)ll;
                split2(p0[3], hh, ll); ph[3] = (short)hh; pl[3] = (short)ll;
                split2(p1[0], hh, ll); ph[4] = (short)hh; pl[4] = (short)ll;
                split2(p1[1], hh, ll); ph[5] = (short)hh; pl[5] = (short)ll;
                split2(p1[2], hh, ll); ph[6] = (short)hh; pl[6] = (short)ll;
                split2(p1[3], hh, ll); ph[7] = (short)hh; pl[7] = (short)ll;
            }
            const size_t koff = (size_t)(c * 64 + ks * 32);
#pragma unroll
            for (int nt = 0; nt < 4; nt++) {
                const short8 bh = *(const short8*)(vbh + (size_t)nt * 16 * SL + koff);
                const short8 bl = *(const short8*)(vbl + (size_t)nt * 16 * SL + koff);
                oac[nt] = __builtin_amdgcn_mfma_f32_16x16x32_bf16(pl, bh, oac[nt], 0, 0, 0);
                oac[nt] = __builtin_amdgcn_mfma_f32_16x16x32_bf16(ph, bl, oac[nt], 0, 0, 0);
                oac[nt] = __builtin_amdgcn_mfma_f32_16x16x32_bf16(ph, bh, oac[nt], 0, 0, 0);
            }
        }
    }

    // ---- O combine across 4 col-quarters (reuse Pf as [wave][16][64] f32) ----
    __syncthreads();   // all waves done with their Pf chunks
#pragma unroll
    for (int nt = 0; nt < 4; nt++) {
        Pf[wave][quad * 4 + 0][nt * 16 + l16] = oac[nt][0];
        Pf[wave][quad * 4 + 1][nt * 16 + l16] = oac[nt][1];
        Pf[wave][quad * 4 + 2][nt * 16 + l16] = oac[nt][2];
        Pf[wave][quad * 4 + 3][nt * 16 + l16] = oac[nt][3];
    }
    __syncthreads();
    {
        const int r  = tid >> 4;            // 0..31
        const int dc = (tid & 15) * 4;      // 0..60
        const int rgc = r >> 4, rl = r & 15;
        short4v h4, l4;
#pragma unroll
        for (int i = 0; i < 4; i++) {
            const float v = Pf[rgc * 4 + 0][rl][dc + i] + Pf[rgc * 4 + 1][rl][dc + i]
                          + Pf[rgc * 4 + 2][rl][dc + i] + Pf[rgc * 4 + 3][rl][dc + i];
            unsigned short hh, ll;
            split2(v, hh, ll);
            h4[i] = (short)hh;
            l4[i] = (short)ll;
        }
        const size_t oidx = ((size_t)n * SL + (m0 + r)) * ED + h * DKH + dc;
        *(short4v*)(Oh + oidx) = h4;
        *(short4v*)(Ol + oidx) = l4;
    }
}

// ---- output projection ----
__global__ __launch_bounds__(256)
void k_outproj(const unsigned short* __restrict__ Ah, const unsigned short* __restrict__ Al,
               const unsigned short* __restrict__ Wh, const unsigned short* __restrict__ Wl,
               const float* __restrict__ bias, float* __restrict__ out)
{
    __shared__ unsigned short smem[(128 + 128) * 128];
    const int m0 = blockIdx.x * 128;
    const int n0 = blockIdx.y * 128;
    f32x4 acc[4][4];
    gemm_core3<true, 128, 128, 2, 2, 4, 4>(smem, nullptr, Ah, Al, ED,
                                           Wh, Wl, ED, ED, m0, n0, acc);

    const int tid = threadIdx.x, wave = tid >> 6, lane = tid & 63;
    const int quad = lane >> 4, l16 = lane & 15;
    const int wr = wave >> 1, wc = wave & 1;
#pragma unroll
    for (int jt = 0; jt < 4; jt++) {
        const int col = n0 + wc * 64 + jt * 16 + l16;
        const float b = bias[col];
#pragma unroll
        for (int g = 0; g < 4; g++) {
#pragma unroll
            for (int rr = 0; rr < 4; rr++) {
                const int m = m0 + wr * 64 + g * 16 + quad * 4 + rr;
                out[(size_t)m * ED + col] = acc[g][jt][rr] + b;
            }
        }
    }
}

extern "C" void kernel_launch(void* const* d_in, const int* in_sizes, int n_in,
                              void* d_out, int out_size, void* d_ws, size_t ws_size,
                              hipStream_t stream) {
    const float* q    = (const float*)d_in[0];
    const float* k    = (const float*)d_in[1];
    const float* v    = (const float*)d_in[2];
    const int*   mask = (const int*)d_in[3];
    const float* wq = (const float*)d_in[4];
    const float* bq = (const float*)d_in[5];
    const float* wk = (const float*)d_in[6];
    const float* bk = (const float*)d_in[7];
    const float* wv = (const float*)d_in[8];
    const float* bv = (const float*)d_in[9];
    const float* wo = (const float*)d_in[10];
    const float* bo = (const float*)d_in[11];

    float* out  = (float*)d_out;
    float* attn = out + (size_t)NB * SL * ED;   // second output: (N,H,S,S)

    unsigned short* w = (unsigned short*)d_ws;
    const size_t WPL = (size_t)ED * ED;
    unsigned short* wqT_h = w + 0 * WPL;
    unsigned short* wqT_l = w + 1 * WPL;
    unsigned short* wkT_h = w + 2 * WPL;
    unsigned short* wkT_l = w + 3 * WPL;
    unsigned short* wvT_h = w + 4 * WPL;
    unsigned short* wvT_l = w + 5 * WPL;
    unsigned short* woT_h = w + 6 * WPL;
    unsigned short* woT_l = w + 7 * WPL;
    unsigned short* base  = w + 8 * WPL;
    const size_t HPL = (size_t)NB * NH * SL * DKH;
    unsigned short* qh_h = base + 0 * HPL;
    unsigned short* qh_l = base + 1 * HPL;
    unsigned short* kh_h = base + 2 * HPL;
    unsigned short* kh_l = base + 3 * HPL;
    unsigned short* vT_h = base + 4 * HPL;
    unsigned short* vT_l = base + 5 * HPL;
    unsigned short* oh_h = qh_h;   // reuse: qh dead after fused attn
    unsigned short* oh_l = qh_l;

    const dim3 blk(256);
    const dim3 gw(ED / 64, ED / 64);
    hipLaunchKernelGGL(k_wsplitT, gw, blk, 0, stream, wq, wqT_h, wqT_l);
    hipLaunchKernelGGL(k_wsplitT, gw, blk, 0, stream, wk, wkT_h, wkT_l);
    hipLaunchKernelGGL(k_wsplitT, gw, blk, 0, stream, wv, wvT_h, wvT_l);
    hipLaunchKernelGGL(k_wsplitT, gw, blk, 0, stream, wo, woT_h, woT_l);

    const dim3 gproj(8192 / 128, ED / 128);
    hipLaunchKernelGGL(k_projQK, gproj, blk, 0, stream, q, wqT_h, wqT_l, bq, qh_h, qh_l);
    hipLaunchKernelGGL(k_projQK, gproj, blk, 0, stream, k, wkT_h, wkT_l, bk, kh_h, kh_l);

    const dim3 gprojV(8192 / 128, ED / 64);
    hipLaunchKernelGGL(k_projV, gprojV, blk, 0, stream, v, wvT_h, wvT_l, bv, vT_h, vT_l);

    const dim3 gfa(SL / 32, NB * NH);               // (32, 128) blocks of 512 threads
    hipLaunchKernelGGL(k_attn_fused, gfa, dim3(512), 0, stream,
                       qh_h, qh_l, kh_h, kh_l, vT_h, vT_l, mask, attn, oh_h, oh_l);

    hipLaunchKernelGGL(k_outproj, gproj, blk, 0, stream, oh_h, oh_l, woT_h, woT_l, bo, out);
}

// Round 5
// 1444.875 us; speedup vs baseline: 1.0806x; 1.0806x over previous
//
#include <hip/hip_runtime.h>
#include <cstdint>
#include <cstddef>

#define NB 8
#define SL 1024
#define ED 1024
#define NH 16
#define DKH 64

typedef __attribute__((ext_vector_type(4))) float f32x4;
typedef __attribute__((ext_vector_type(8))) short short8;
typedef __attribute__((ext_vector_type(4))) short short4v;

__device__ __forceinline__ unsigned short bf16_rn(float x) {
    unsigned int u = __float_as_uint(x);
    u += 0x7FFFu + ((u >> 16) & 1u);
    return (unsigned short)(u >> 16);
}
__device__ __forceinline__ float bf16_f(unsigned short h) {
    return __uint_as_float(((unsigned int)h) << 16);
}
__device__ __forceinline__ void split2(float x, unsigned short& hi, unsigned short& lo) {
    unsigned short h = bf16_rn(x);
    hi = h;
    lo = bf16_rn(x - bf16_f(h));
}

// async global->LDS DMA, 16B per lane (linear dest = base + lane*16).
__device__ __forceinline__ void dma16(const unsigned short* src, unsigned short* dst) {
    __builtin_amdgcn_global_load_lds(
        (const __attribute__((address_space(1))) void*)src,
        (__attribute__((address_space(3))) void*)dst,
        16, 0, 0);
}

template<int ROWS>
__device__ __forceinline__ void dma_plane(
    const unsigned short* __restrict__ g, unsigned short* l,
    int ld, int r0, int k0, int wave, int lane)
{
    for (int i = wave; i < ROWS / 16; i += 4) {
        const unsigned short* src =
            g + (size_t)(r0 + i * 16 + (lane >> 2)) * ld + k0 + (lane & 3) * 8;
        dma16(src, l + i * 512);
    }
}

// -------- GEMM core: BM x BN, BK=32, 256 thr, dbuf LDS, both operands pre-split (DMA) --------
// A planes [m][k] (lda), B planes [n][k] (ldb). Verified layouts:
// A[m=l16][k=quad*8+j], B[n=l16][k=quad*8+j], C col=l16, row=quad*4+r.
template<int BM, int BN, int WR, int WC, int ROWG, int COLT>
__device__ __forceinline__ void gemm_core4(
    unsigned short* smem,
    const unsigned short* __restrict__ Ahg, const unsigned short* __restrict__ Alg,
    int lda,
    const unsigned short* __restrict__ Bhg, const unsigned short* __restrict__ Blg,
    int ldb, int Kd, int m0, int n0,
    f32x4 (&acc)[ROWG][COLT])
{
    static_assert(WR * WC == 4, "4 waves");
    static_assert(16 * ROWG * WR == BM, "rows");
    static_assert(16 * COLT * WC == BN, "cols");

    constexpr int ASZ = BM * 32;
    constexpr int BSZ = BN * 32;
    unsigned short* Ah = smem;
    unsigned short* Al = smem + 2 * ASZ;
    unsigned short* Bh = smem + 4 * ASZ;
    unsigned short* Bl = smem + 4 * ASZ + 2 * BSZ;

    const int tid  = threadIdx.x;
    const int wave = tid >> 6;
    const int lane = tid & 63;
    const int quad = lane >> 4;
    const int l16  = lane & 15;
    const int wr   = wave / WC;
    const int wc   = wave % WC;

#pragma unroll
    for (int g = 0; g < ROWG; g++)
#pragma unroll
        for (int jt = 0; jt < COLT; jt++) acc[g][jt] = (f32x4)(0.0f);

    auto stage = [&](int b, int kk) {
        dma_plane<BM>(Ahg, Ah + b * ASZ, lda, m0, kk, wave, lane);
        dma_plane<BM>(Alg, Al + b * ASZ, lda, m0, kk, wave, lane);
        dma_plane<BN>(Bhg, Bh + b * BSZ, ldb, n0, kk, wave, lane);
        dma_plane<BN>(Blg, Bl + b * BSZ, ldb, n0, kk, wave, lane);
    };

    stage(0, 0);
    __syncthreads();   // drains vmcnt -> DMA complete

    int buf = 0;
    for (int k0 = 0; k0 < Kd; k0 += 32) {
        const int nk = k0 + 32;
        if (nk < Kd) stage(buf ^ 1, nk);
        const unsigned short* pAh = Ah + buf * ASZ;
        const unsigned short* pAl = Al + buf * ASZ;
        const unsigned short* pBh = Bh + buf * BSZ;
        const unsigned short* pBl = Bl + buf * BSZ;
        short8 ah[ROWG], al[ROWG];
#pragma unroll
        for (int g = 0; g < ROWG; g++) {
            const int row = wr * (16 * ROWG) + g * 16 + l16;
            ah[g] = *(const short8*)&pAh[row * 32 + quad * 8];
            al[g] = *(const short8*)&pAl[row * 32 + quad * 8];
        }
#pragma unroll
        for (int jt = 0; jt < COLT; jt++) {
            const int brow = wc * (16 * COLT) + jt * 16 + l16;
            const short8 bh = *(const short8*)&pBh[brow * 32 + quad * 8];
            const short8 bl = *(const short8*)&pBl[brow * 32 + quad * 8];
#pragma unroll
            for (int g = 0; g < ROWG; g++) {
                acc[g][jt] = __builtin_amdgcn_mfma_f32_16x16x32_bf16(al[g], bh, acc[g][jt], 0, 0, 0);
                acc[g][jt] = __builtin_amdgcn_mfma_f32_16x16x32_bf16(ah[g], bl, acc[g][jt], 0, 0, 0);
                acc[g][jt] = __builtin_amdgcn_mfma_f32_16x16x32_bf16(ah[g], bh, acc[g][jt], 0, 0, 0);
            }
        }
        __syncthreads();
        buf ^= 1;
    }
}

// ---- weight transpose + split: W [k][n] -> WT hi/lo [n][k] ----
__global__ __launch_bounds__(256)
void k_wsplitT(const float* __restrict__ W,
               unsigned short* __restrict__ Th, unsigned short* __restrict__ Tl)
{
    __shared__ float tile[64 * 65];
    const int n0 = blockIdx.x * 64;
    const int k0 = blockIdx.y * 64;
    const int tid = threadIdx.x;
    for (int i = tid; i < 64 * 64; i += 256) {
        const int rk = i >> 6, cn = i & 63;
        tile[rk * 65 + cn] = W[(size_t)(k0 + rk) * ED + n0 + cn];
    }
    __syncthreads();
    for (int i = tid; i < 64 * 64; i += 256) {
        const int rn = i >> 6, ck = i & 63;
        unsigned short h, l;
        split2(tile[ck * 65 + rn], h, l);
        Th[(size_t)(n0 + rn) * ED + k0 + ck] = h;
        Tl[(size_t)(n0 + rn) * ED + k0 + ck] = l;
    }
}

// ---- X pre-split: fp32 [R][E] -> hi/lo planes (split ONCE, removes VALU from GEMM K-loops) ----
__global__ __launch_bounds__(256)
void k_splitX(const float* __restrict__ X,
              unsigned short* __restrict__ Xh, unsigned short* __restrict__ Xl)
{
    const size_t i = ((size_t)blockIdx.x * 256 + threadIdx.x) * 8;
    const float4 v0 = *(const float4*)(X + i);
    const float4 v1 = *(const float4*)(X + i + 4);
    short8 h8, l8;
    unsigned short h, l;
    split2(v0.x, h, l); h8[0] = (short)h; l8[0] = (short)l;
    split2(v0.y, h, l); h8[1] = (short)h; l8[1] = (short)l;
    split2(v0.z, h, l); h8[2] = (short)h; l8[2] = (short)l;
    split2(v0.w, h, l); h8[3] = (short)h; l8[3] = (short)l;
    split2(v1.x, h, l); h8[4] = (short)h; l8[4] = (short)l;
    split2(v1.y, h, l); h8[5] = (short)h; l8[5] = (short)l;
    split2(v1.z, h, l); h8[6] = (short)h; l8[6] = (short)l;
    split2(v1.w, h, l); h8[7] = (short)h; l8[7] = (short)l;
    *(short8*)(Xh + i) = h8;
    *(short8*)(Xl + i) = l8;
}

// ---- mask bit-pack: int32 (N,S,S) -> 1 bit/elem, word = t/32, bit = t%32 ----
__global__ __launch_bounds__(256)
void k_maskpack(const int* __restrict__ m, unsigned int* __restrict__ mb)
{
    const size_t w = (size_t)blockIdx.x * 256 + threadIdx.x;
    const int4* p = (const int4*)(m + w * 32);
    unsigned int b = 0;
#pragma unroll
    for (int i = 0; i < 8; i++) {
        const int4 q4 = p[i];
        b |= (q4.x ? 1u : 0u) << (i * 4 + 0);
        b |= (q4.y ? 1u : 0u) << (i * 4 + 1);
        b |= (q4.z ? 1u : 0u) << (i * 4 + 2);
        b |= (q4.w ? 1u : 0u) << (i * 4 + 3);
    }
    mb[w] = b;
}

// ---- q/k projection (pure DMA core): writes pre-split heads layout [n,h,s,d] hi/lo ----
__global__ __launch_bounds__(256)
void k_projQK(const unsigned short* __restrict__ Xh, const unsigned short* __restrict__ Xl,
              const unsigned short* __restrict__ Wh, const unsigned short* __restrict__ Wl,
              const float* __restrict__ bias,
              unsigned short* __restrict__ Oh, unsigned short* __restrict__ Ol)
{
    __shared__ unsigned short smem[(128 + 128) * 128];
    const int m0 = blockIdx.x * 128;
    const int n0 = blockIdx.y * 128;
    f32x4 acc[4][4];
    gemm_core4<128, 128, 2, 2, 4, 4>(smem, Xh, Xl, ED, Wh, Wl, ED, ED, m0, n0, acc);

    const int tid = threadIdx.x, wave = tid >> 6, lane = tid & 63;
    const int quad = lane >> 4, l16 = lane & 15;
    const int wr = wave >> 1, wc = wave & 1;
#pragma unroll
    for (int jt = 0; jt < 4; jt++) {
        const int col = n0 + wc * 64 + jt * 16 + l16;
        const int h = col >> 6, d = col & 63;
        const float b = bias[col];
#pragma unroll
        for (int g = 0; g < 4; g++) {
#pragma unroll
            for (int rr = 0; rr < 4; rr++) {
                const int m = m0 + wr * 64 + g * 16 + quad * 4 + rr;
                const int n = m >> 10, s = m & 1023;
                const size_t idx = (((size_t)(n * NH + h)) * SL + s) * DKH + d;
                unsigned short hh, ll;
                split2(acc[g][jt][rr] + b, hh, ll);
                Oh[idx] = hh;
                Ol[idx] = ll;
            }
        }
    }
}

// ---- v projection: writes pre-split V in PV-frag-dense layout v3[head][t/32][d][t%32] ----
__global__ __launch_bounds__(256)
void k_projV(const unsigned short* __restrict__ Xh, const unsigned short* __restrict__ Xl,
             const unsigned short* __restrict__ Wh, const unsigned short* __restrict__ Wl,
             const float* __restrict__ bias,
             unsigned short* __restrict__ Th, unsigned short* __restrict__ Tl)
{
    __shared__ unsigned short smem[(128 + 64) * 128];   // 48KB; reused as T (33KB)
    const int m0 = blockIdx.x * 128;
    const int n0 = blockIdx.y * 64;
    f32x4 acc[2][4];
    gemm_core4<128, 64, 4, 1, 2, 4>(smem, Xh, Xl, ED, Wh, Wl, ED, ED, m0, n0, acc);

    unsigned int* T = (unsigned int*)smem;   // [128][65] packed (hi | lo<<16), [s_local][d]
    const int tid = threadIdx.x, wave = tid >> 6, lane = tid & 63;
    const int quad = lane >> 4, l16 = lane & 15;
#pragma unroll
    for (int jt = 0; jt < 4; jt++) {
        const int d = jt * 16 + l16;
        const float b = bias[n0 + d];
#pragma unroll
        for (int g = 0; g < 2; g++) {
#pragma unroll
            for (int rr = 0; rr < 4; rr++) {
                const int sl = wave * 32 + g * 16 + quad * 4 + rr;
                unsigned short hh, ll;
                split2(acc[g][jt][rr] + b, hh, ll);
                T[sl * 65 + d] = (unsigned int)hh | ((unsigned int)ll << 16);
            }
        }
    }
    __syncthreads();
    const int d  = tid >> 2;            // 0..63
    const int sc = (tid & 3) * 32;      // 0,32,64,96
    const int ghead = (m0 >> 10) * NH + (n0 >> 6);
    const int sblk = ((m0 & 1023) + sc) >> 5;
    const size_t base = (size_t)ghead * (SL * DKH) + ((size_t)sblk * DKH + d) * 32;
#pragma unroll
    for (int c = 0; c < 4; c++) {
        short8 h8, l8;
#pragma unroll
        for (int i = 0; i < 8; i++) {
            const unsigned int u = T[(sc + c * 8 + i) * 65 + d];
            h8[i] = (short)(u & 0xFFFFu);
            l8[i] = (short)(u >> 16);
        }
        *(short8*)(Th + base + c * 8) = h8;
        *(short8*)(Tl + base + c * 8) = l8;
    }
}

// ==== FUSED attention v2: 256 thr, 16 q-rows x 1 head; wave cq owns 256-col quarter ====
#define PFW 68
__global__ __launch_bounds__(256, 4)
void k_attn_fused(const unsigned short* __restrict__ qh_h, const unsigned short* __restrict__ qh_l,
                  const unsigned short* __restrict__ kh_h, const unsigned short* __restrict__ kh_l,
                  const unsigned short* __restrict__ v3_h, const unsigned short* __restrict__ v3_l,
                  const unsigned int* __restrict__ maskb, float* __restrict__ attn,
                  unsigned short* __restrict__ Oh, unsigned short* __restrict__ Ol)
{
    __shared__ float Pf[4][16][PFW];   // per-wave chunk buffer; reused for O-combine
    __shared__ float MX[4][16];
    __shared__ float SMm[4][16];

    const int head = blockIdx.y;
    const int n = head >> 4, h = head & 15;
    const int m0 = blockIdx.x * 16;
    const int tid = threadIdx.x, cq = tid >> 6, lane = tid & 63;
    const int quad = lane >> 4, l16 = lane & 15;
    const size_t hb = (size_t)head * SL * DKH;

    // ---- Q A-frags ----
    short8 qa_h[2], qa_l[2];
    {
        const unsigned short* qrh = qh_h + hb + (size_t)(m0 + l16) * DKH + quad * 8;
        const unsigned short* qrl = qh_l + hb + (size_t)(m0 + l16) * DKH + quad * 8;
        qa_h[0] = *(const short8*)(qrh);
        qa_l[0] = *(const short8*)(qrl);
        qa_h[1] = *(const short8*)(qrh + 32);
        qa_l[1] = *(const short8*)(qrl + 32);
    }

    // ---- QK^T: 16 col-tiles of 16 in this wave's quarter, K=64 ----
    f32x4 acc[16];
    {
        const unsigned short* kbh = kh_h + hb + (size_t)(cq * 256 + l16) * DKH + quad * 8;
        const unsigned short* kbl = kh_l + hb + (size_t)(cq * 256 + l16) * DKH + quad * 8;
#pragma unroll
        for (int tt = 0; tt < 16; tt++) {
            const size_t toff = (size_t)tt * 16 * DKH;
            const short8 bh0 = *(const short8*)(kbh + toff);
            const short8 bl0 = *(const short8*)(kbl + toff);
            const short8 bh1 = *(const short8*)(kbh + toff + 32);
            const short8 bl1 = *(const short8*)(kbl + toff + 32);
            f32x4 a = (f32x4)(0.0f);
            a = __builtin_amdgcn_mfma_f32_16x16x32_bf16(qa_l[0], bh0, a, 0, 0, 0);
            a = __builtin_amdgcn_mfma_f32_16x16x32_bf16(qa_h[0], bl0, a, 0, 0, 0);
            a = __builtin_amdgcn_mfma_f32_16x16x32_bf16(qa_h[0], bh0, a, 0, 0, 0);
            a = __builtin_amdgcn_mfma_f32_16x16x32_bf16(qa_l[1], bh1, a, 0, 0, 0);
            a = __builtin_amdgcn_mfma_f32_16x16x32_bf16(qa_h[1], bl1, a, 0, 0, 0);
            a = __builtin_amdgcn_mfma_f32_16x16x32_bf16(qa_h[1], bh1, a, 0, 0, 0);
            acc[tt] = a;
        }
    }

    // ---- scale + mask (bit-packed: 2 uint4 loads per row, broadcast across l16) ----
    {
        const unsigned int* mw = maskb + ((size_t)n * SL + (m0 + quad * 4)) * (SL / 32) + cq * 8;
        const unsigned int bmlo = 1u << l16;
        const unsigned int bmhi = 1u << (16 + l16);
#pragma unroll
        for (int rr = 0; rr < 4; rr++) {
            const uint4 wa = *(const uint4*)(mw + (size_t)rr * (SL / 32));
            const uint4 wb = *(const uint4*)(mw + (size_t)rr * (SL / 32) + 4);
            const unsigned int wd[8] = {wa.x, wa.y, wa.z, wa.w, wb.x, wb.y, wb.z, wb.w};
#pragma unroll
            for (int tt = 0; tt < 16; tt++) {
                float v = acc[tt][rr] * 0.125f;
                if (wd[tt >> 1] & ((tt & 1) ? bmhi : bmlo)) v = -1e9f;
                acc[tt][rr] = v;
            }
        }
    }

    // ---- row max (quarter-local shuffle, cross-quarter via LDS) ----
    float m4[4];
#pragma unroll
    for (int rr = 0; rr < 4; rr++) {
        float mx = -3.4e38f;
#pragma unroll
        for (int tt = 0; tt < 16; tt++) mx = fmaxf(mx, acc[tt][rr]);
#pragma unroll
        for (int o = 8; o > 0; o >>= 1) mx = fmaxf(mx, __shfl_xor(mx, o));
        m4[rr] = mx;
    }
    if (l16 < 4) {
        const float v = (l16 == 0) ? m4[0] : (l16 == 1) ? m4[1] : (l16 == 2) ? m4[2] : m4[3];
        MX[cq][quad * 4 + l16] = v;
    }
    __syncthreads();
    float mc[4], sum4[4];
#pragma unroll
    for (int rr = 0; rr < 4; rr++) {
        const int r = quad * 4 + rr;
        mc[rr] = fmaxf(fmaxf(MX[0][r], MX[1][r]), fmaxf(MX[2][r], MX[3][r]));
        sum4[rr] = 0.0f;
    }

    // ---- exp + row sum ----
#pragma unroll
    for (int tt = 0; tt < 16; tt++) {
#pragma unroll
        for (int rr = 0; rr < 4; rr++) {
            const float p = __expf(acc[tt][rr] - mc[rr]);
            acc[tt][rr] = p;
            sum4[rr] += p;
        }
    }
#pragma unroll
    for (int rr = 0; rr < 4; rr++) {
#pragma unroll
        for (int o = 8; o > 0; o >>= 1) sum4[rr] += __shfl_xor(sum4[rr], o);
    }
    if (l16 < 4) {
        const float v = (l16 == 0) ? sum4[0] : (l16 == 1) ? sum4[1] : (l16 == 2) ? sum4[2] : sum4[3];
        SMm[cq][quad * 4 + l16] = v;
    }
    __syncthreads();
    float inv[4];
#pragma unroll
    for (int rr = 0; rr < 4; rr++) {
        const int r = quad * 4 + rr;
        inv[rr] = 1.0f / (SMm[0][r] + SMm[1][r] + SMm[2][r] + SMm[3][r]);
    }

    // ---- PV + attn write, 4 chunks of 64 t-cols ----
    f32x4 oac[4];
#pragma unroll
    for (int nt = 0; nt < 4; nt++) oac[nt] = (f32x4)(0.0f);

    const unsigned short* v3bh = v3_h + (size_t)head * (SL * DKH);
    const unsigned short* v3bl = v3_l + (size_t)head * (SL * DKH);
    float* aw = attn + ((size_t)head * SL + m0) * SL + cq * 256;
    const int srow = lane >> 2;
    const int sseg = (lane & 3) * 16;

#pragma unroll
    for (int c = 0; c < 4; c++) {
#pragma unroll
        for (int i = 0; i < 4; i++) {
            const int tt = c * 4 + i;
            Pf[cq][quad * 4 + 0][i * 16 + l16] = acc[tt][0] * inv[0];
            Pf[cq][quad * 4 + 1][i * 16 + l16] = acc[tt][1] * inv[1];
            Pf[cq][quad * 4 + 2][i * 16 + l16] = acc[tt][2] * inv[2];
            Pf[cq][quad * 4 + 3][i * 16 + l16] = acc[tt][3] * inv[3];
        }
        // coalesced NON-TEMPORAL attn store (keep K/V/mask in L2)
        {
            float* dst = aw + (size_t)srow * SL + c * 64 + sseg;
            const float* srcb = &Pf[cq][srow][sseg];
            __builtin_nontemporal_store(*(const f32x4*)(srcb + 0),  (f32x4*)(dst + 0));
            __builtin_nontemporal_store(*(const f32x4*)(srcb + 4),  (f32x4*)(dst + 4));
            __builtin_nontemporal_store(*(const f32x4*)(srcb + 8),  (f32x4*)(dst + 8));
            __builtin_nontemporal_store(*(const f32x4*)(srcb + 12), (f32x4*)(dst + 12));
        }
        // A-frag transpose read (split once) + PV MFMA; V frags dense 1KB/instr
#pragma unroll
        for (int ks = 0; ks < 2; ks++) {
            const float* pr = &Pf[cq][l16][ks * 32 + quad * 8];
            const f32x4 p0 = *(const f32x4*)(pr + 0);
            const f32x4 p1 = *(const f32x4*)(pr + 4);
            short8 ph, pl;
            {
                unsigned short hh, ll;
                split2(p0[0], hh, ll); ph[0] = (short)hh; pl[0] = (short)ll;
                split2(p0[1], hh, ll); ph[1] = (short)hh; pl[1] = (short)ll;
                split2(p0[2], hh, ll); ph[2] = (short)hh; pl[2] = (short)ll;
                split2(p0[3], hh, ll); ph[3] = (short)hh; pl[3] = (short)ll;
                split2(p1[0], hh, ll); ph[4] = (short)hh; pl[4] = (short)ll;
                split2(p1[1], hh, ll); ph[5] = (short)hh; pl[5] = (short)ll;
                split2(p1[2], hh, ll); ph[6] = (short)hh; pl[6] = (short)ll;
                split2(p1[3], hh, ll); ph[7] = (short)hh; pl[7] = (short)ll;
            }
            const int tc = cq * 8 + c * 2 + ks;
#pragma unroll
            for (int nt = 0; nt < 4; nt++) {
                const size_t vo = ((size_t)(tc * 64 + nt * 16 + l16)) * 32 + quad * 8;
                const short8 bh = *(const short8*)(v3bh + vo);
                const short8 bl = *(const short8*)(v3bl + vo);
                oac[nt] = __builtin_amdgcn_mfma_f32_16x16x32_bf16(pl, bh, oac[nt], 0, 0, 0);
                oac[nt] = __builtin_amdgcn_mfma_f32_16x16x32_bf16(ph, bl, oac[nt], 0, 0, 0);
                oac[nt] = __builtin_amdgcn_mfma_f32_16x16x32_bf16(ph, bh, oac[nt], 0, 0, 0);
            }
        }
    }

    // ---- O combine across 4 quarters ----
    __syncthreads();
#pragma unroll
    for (int nt = 0; nt < 4; nt++) {
        Pf[cq][quad * 4 + 0][nt * 16 + l16] = oac[nt][0];
        Pf[cq][quad * 4 + 1][nt * 16 + l16] = oac[nt][1];
        Pf[cq][quad * 4 + 2][nt * 16 + l16] = oac[nt][2];
        Pf[cq][quad * 4 + 3][nt * 16 + l16] = oac[nt][3];
    }
    __syncthreads();
    {
        const int r  = tid >> 4;            // 0..15
        const int dc = (tid & 15) * 4;      // 0..60
        short4v h4, l4;
#pragma unroll
        for (int i = 0; i < 4; i++) {
            const float v = Pf[0][r][dc + i] + Pf[1][r][dc + i]
                          + Pf[2][r][dc + i] + Pf[3][r][dc + i];
            unsigned short hh, ll;
            split2(v, hh, ll);
            h4[i] = (short)hh;
            l4[i] = (short)ll;
        }
        const size_t oidx = ((size_t)n * SL + m0 + r) * ED + h * DKH + dc;
        *(short4v*)(Oh + oidx) = h4;
        *(short4v*)(Ol + oidx) = l4;
    }
}

// ---- output projection: both operands pre-split (DMA) ----
__global__ __launch_bounds__(256)
void k_outproj(const unsigned short* __restrict__ Ah, const unsigned short* __restrict__ Al,
               const unsigned short* __restrict__ Wh, const unsigned short* __restrict__ Wl,
               const float* __restrict__ bias, float* __restrict__ out)
{
    __shared__ unsigned short smem[(128 + 128) * 128];
    const int m0 = blockIdx.x * 128;
    const int n0 = blockIdx.y * 128;
    f32x4 acc[4][4];
    gemm_core4<128, 128, 2, 2, 4, 4>(smem, Ah, Al, ED, Wh, Wl, ED, ED, m0, n0, acc);

    const int tid = threadIdx.x, wave = tid >> 6, lane = tid & 63;
    const int quad = lane >> 4, l16 = lane & 15;
    const int wr = wave >> 1, wc = wave & 1;
#pragma unroll
    for (int jt = 0; jt < 4; jt++) {
        const int col = n0 + wc * 64 + jt * 16 + l16;
        const float b = bias[col];
#pragma unroll
        for (int g = 0; g < 4; g++) {
#pragma unroll
            for (int rr = 0; rr < 4; rr++) {
                const int m = m0 + wr * 64 + g * 16 + quad * 4 + rr;
                out[(size_t)m * ED + col] = acc[g][jt][rr] + b;
            }
        }
    }
}

extern "C" void kernel_launch(void* const* d_in, const int* in_sizes, int n_in,
                              void* d_out, int out_size, void* d_ws, size_t ws_size,
                              hipStream_t stream) {
    const float* q    = (const float*)d_in[0];
    const float* k    = (const float*)d_in[1];
    const float* v    = (const float*)d_in[2];
    const int*   mask = (const int*)d_in[3];
    const float* wq = (const float*)d_in[4];
    const float* bq = (const float*)d_in[5];
    const float* wk = (const float*)d_in[6];
    const float* bk = (const float*)d_in[7];
    const float* wv = (const float*)d_in[8];
    const float* bv = (const float*)d_in[9];
    const float* wo = (const float*)d_in[10];
    const float* bo = (const float*)d_in[11];

    float* out  = (float*)d_out;
    float* attn = out + (size_t)NB * SL * ED;              // (N,H,S,S) fp32, 512 MiB
    const size_t attnElems = (size_t)NB * NH * SL * SL;

    // ---- X-split scratch lives in the DEAD TAIL of the attn buffer (read by projections,
    //      overwritten later by k_attn_fused) -> zero ws cost ----
    const size_t HPL = (size_t)NB * NH * SL * DKH;         // 8,388,608 elems / plane
    unsigned short* xs = (unsigned short*)(attn + attnElems) - 6 * HPL;
    unsigned short* xq_h = xs + 0 * HPL;
    unsigned short* xq_l = xs + 1 * HPL;
    unsigned short* xk_h = xs + 2 * HPL;
    unsigned short* xk_l = xs + 3 * HPL;
    unsigned short* xv_h = xs + 4 * HPL;
    unsigned short* xv_l = xs + 5 * HPL;

    // ---- workspace map ----
    unsigned short* w = (unsigned short*)d_ws;
    const size_t WPL = (size_t)ED * ED;
    unsigned short* wqT_h = w + 0 * WPL;
    unsigned short* wqT_l = w + 1 * WPL;
    unsigned short* wkT_h = w + 2 * WPL;
    unsigned short* wkT_l = w + 3 * WPL;
    unsigned short* wvT_h = w + 4 * WPL;
    unsigned short* wvT_l = w + 5 * WPL;
    unsigned short* woT_h = w + 6 * WPL;
    unsigned short* woT_l = w + 7 * WPL;
    unsigned short* base  = w + 8 * WPL;
    unsigned short* qh_h = base + 0 * HPL;
    unsigned short* qh_l = base + 1 * HPL;
    unsigned short* kh_h = base + 2 * HPL;
    unsigned short* kh_l = base + 3 * HPL;
    unsigned short* v3_h = base + 4 * HPL;
    unsigned short* v3_l = base + 5 * HPL;
    unsigned int*  maskb = (unsigned int*)(base + 6 * HPL);   // 1 MiB
    unsigned short* afterMb = base + 6 * HPL + (NB * SL * SL / 32) * 2;  // in shorts

    // oh planes: dedicated if ws is large enough (race-free), else alias qh (empirically safe:
    // a batch's 1024 blocks are co-resident; Q-reads complete before same-batch O-writes).
    const size_t needBytes = (size_t)(afterMb - w) * 2 + 2 * HPL * 2;
    unsigned short* oh_h;
    unsigned short* oh_l;
    if (ws_size >= needBytes) {
        oh_h = afterMb;
        oh_l = afterMb + HPL;
    } else {
        oh_h = qh_h;
        oh_l = qh_l;
    }

    const dim3 blk(256);

    // 1. pre-split X (q,k,v)
    const dim3 gsx((NB * SL * ED) / (8 * 256));            // 4096
    hipLaunchKernelGGL(k_splitX, gsx, blk, 0, stream, q, xq_h, xq_l);
    hipLaunchKernelGGL(k_splitX, gsx, blk, 0, stream, k, xk_h, xk_l);
    hipLaunchKernelGGL(k_splitX, gsx, blk, 0, stream, v, xv_h, xv_l);

    // 2. weight transpose+split
    const dim3 gw(ED / 64, ED / 64);
    hipLaunchKernelGGL(k_wsplitT, gw, blk, 0, stream, wq, wqT_h, wqT_l);
    hipLaunchKernelGGL(k_wsplitT, gw, blk, 0, stream, wk, wkT_h, wkT_l);
    hipLaunchKernelGGL(k_wsplitT, gw, blk, 0, stream, wv, wvT_h, wvT_l);
    hipLaunchKernelGGL(k_wsplitT, gw, blk, 0, stream, wo, woT_h, woT_l);

    // 3. mask bit-pack
    hipLaunchKernelGGL(k_maskpack, dim3((NB * SL * SL / 32) / 256), blk, 0, stream, mask, maskb);

    // 4. projections (pure-DMA GEMM cores)
    const dim3 gproj(8192 / 128, ED / 128);
    hipLaunchKernelGGL(k_projQK, gproj, blk, 0, stream, xq_h, xq_l, wqT_h, wqT_l, bq, qh_h, qh_l);
    hipLaunchKernelGGL(k_projQK, gproj, blk, 0, stream, xk_h, xk_l, wkT_h, wkT_l, bk, kh_h, kh_l);
    const dim3 gprojV(8192 / 128, ED / 64);
    hipLaunchKernelGGL(k_projV, gprojV, blk, 0, stream, xv_h, xv_l, wvT_h, wvT_l, bv, v3_h, v3_l);

    // 5. fused attention
    const dim3 gfa(SL / 16, NB * NH);                      // (64, 128)
    hipLaunchKernelGGL(k_attn_fused, gfa, blk, 0, stream,
                       qh_h, qh_l, kh_h, kh_l, v3_h, v3_l, maskb, attn, oh_h, oh_l);

    // 6. output projection
    hipLaunchKernelGGL(k_outproj, gproj, blk, 0, stream, oh_h, oh_l, woT_h, woT_l, bo, out);
}